// Round 5
// baseline (316.178 us; speedup 1.0000x reference)
//
#include <hip/hip_runtime.h>

#define N_TOK 16384
#define D 64
#define NC 512
#define KSEL 16

// ---------------- kernel P0: zero out + zero hist + center norms ----------------
__global__ void prep_kernel(float4* __restrict__ out4, int* __restrict__ hist,
                            const float* __restrict__ ctrs, float* __restrict__ c2) {
    int i = blockIdx.x * 256 + threadIdx.x;
    out4[i] = make_float4(0.f, 0.f, 0.f, 0.f);
    if (i < NC) {
        const float4* row = (const float4*)(ctrs + i * D);
        float s = 0.f;
        #pragma unroll
        for (int q = 0; q < D / 4; ++q) {
            float4 v = row[q];
            s += v.x * v.x + v.y * v.y + v.z * v.z + v.w * v.w;
        }
        c2[i] = s;
    } else if (i < 2 * NC) {
        hist[i - NC] = 0;
    }
}

__device__ __forceinline__ unsigned fkey(float f) {
    unsigned u = __float_as_uint(f);
    return (u & 0x80000000u) ? ~u : (u | 0x80000000u);
}
__device__ __forceinline__ float funkey(unsigned k) {
    unsigned u = (k & 0x80000000u) ? (k & 0x7fffffffu) : ~k;
    return __uint_as_float(u);
}

// ---------------- kernel B: dist + top-16 + softmax, lane = token ----------------
// 512 threads = 8 waves; 64 tokens/block (lane L <-> token base+L); wave wi owns
// centers {p*64 + wi*8 .. +7} across 8 phases -> 64 scores/lane in REGISTERS.
// launch_bounds(512,1): VGPR cap 256 so xr[64]+skey[64] stay in registers.
__global__ __launch_bounds__(512, 1) void topk6_kernel(
    const float* __restrict__ x, const float* __restrict__ ctrs,
    const float* __restrict__ c2, float* __restrict__ scores,
    int* __restrict__ sidx, int* __restrict__ hist) {
    __shared__ __align__(16) unsigned char pool[35840];
    float* xs = (float*)pool;                 // [64][68]  17408 B
    float* slab = (float*)(pool + 17408);     // [64][64]  16384 B (phase centers)
    int* lhist = (int*)(pool + 33792);        // [512]      2048 B
    unsigned* mb = (unsigned*)pool;           // [64][132] 33792 B, overlays xs+slab

    const int t = threadIdx.x;
    const int lane = t & 63;
    const int wi = t >> 6;
    const int base = blockIdx.x * 64;

    if (t < NC) lhist[t] = 0;

    // stage x tile -> xs (stride 68: conflict-free b128 per-lane reads)
    #pragma unroll
    for (int i = 0; i < 2; ++i) {
        int e = t + 512 * i;
        int r = e >> 4, j = e & 15;
        float4 v = *(const float4*)(x + (base + r) * D + j * 4);
        *(float4*)(xs + r * 68 + j * 4) = v;
    }
    __syncthreads();

    // own token's x row -> 64 VGPRs
    float xr[64];
    #pragma unroll
    for (int q = 0; q < 16; ++q) {
        float4 v = *(const float4*)(xs + lane * 68 + q * 4);
        xr[4 * q + 0] = v.x; xr[4 * q + 1] = v.y;
        xr[4 * q + 2] = v.z; xr[4 * q + 3] = v.w;
    }

    unsigned skey[64];

    // prefetch phase-0 centers into regs
    float4 pre0, pre1;
    {
        int r0 = t >> 4, j0 = t & 15;
        pre0 = *(const float4*)(ctrs + r0 * D + j0 * 4);
        int e1 = t + 512, r1 = e1 >> 4, j1 = e1 & 15;
        pre1 = *(const float4*)(ctrs + r1 * D + j1 * 4);
    }

    #pragma unroll
    for (int p = 0; p < 8; ++p) {
        __syncthreads();  // slab free (previous phase's reads done)
        {
            int r0 = t >> 4, j0 = t & 15;
            *(float4*)(slab + r0 * D + j0 * 4) = pre0;
            int e1 = t + 512, r1 = e1 >> 4, j1 = e1 & 15;
            *(float4*)(slab + r1 * D + j1 * 4) = pre1;
        }
        if (p < 7) {  // prefetch next phase during compute
            int r0 = t >> 4, j0 = t & 15;
            pre0 = *(const float4*)(ctrs + ((p + 1) * 64 + r0) * D + j0 * 4);
            int e1 = t + 512, r1 = e1 >> 4, j1 = e1 & 15;
            pre1 = *(const float4*)(ctrs + ((p + 1) * 64 + r1) * D + j1 * 4);
        }
        __syncthreads();  // slab ready

        #pragma unroll
        for (int jc = 0; jc < 8; ++jc) {
            const float* row = slab + (wi * 8 + jc) * D;  // wave-uniform broadcast
            float a = 0.f;
            #pragma unroll
            for (int q = 0; q < 16; ++q) {
                float4 w = *(const float4*)(row + q * 4);
                a = fmaf(xr[4 * q + 0], w.x, a);
                a = fmaf(xr[4 * q + 1], w.y, a);
                a = fmaf(xr[4 * q + 2], w.z, a);
                a = fmaf(xr[4 * q + 3], w.w, a);
            }
            int cg = p * 64 + wi * 8 + jc;
            float sc = fmaf(2.f, a, -c2[cg]);   // wave-uniform -> scalar load
            skey[p * 8 + jc] = (fkey(sc) & 0xFFFFFE00u) | (unsigned)cg;
        }
    }

    // per-lane top-16 of 64 keys: masked descending extraction (keys unique)
    unsigned outk[16];
    {
        unsigned prev = 0xFFFFFFFFu;
        #pragma unroll
        for (int r = 0; r < KSEL; ++r) {
            unsigned m = 0u;
            #pragma unroll
            for (int j = 0; j < 64; ++j) {
                unsigned tv = (skey[j] < prev) ? skey[j] : 0u;
                m = m > tv ? m : tv;
            }
            outk[r] = m;
            prev = m;
        }
    }

    __syncthreads();  // slab reads done; xs dead -> mb overlay safe
    {
        uint4* dst = (uint4*)(mb + lane * 132 + wi * 16);
        dst[0] = make_uint4(outk[0], outk[1], outk[2], outk[3]);
        dst[1] = make_uint4(outk[4], outk[5], outk[6], outk[7]);
        dst[2] = make_uint4(outk[8], outk[9], outk[10], outk[11]);
        dst[3] = make_uint4(outk[12], outk[13], outk[14], outk[15]);
    }
    __syncthreads();

    if (wi == 0) {  // 8-way tournament merge per lane (= per token), exact
        unsigned h[8]; int pos[8];
        #pragma unroll
        for (int w = 0; w < 8; ++w) { pos[w] = 0; h[w] = mb[lane * 132 + w * 16]; }
        float vals[16]; int ids[16];
        #pragma unroll
        for (int r = 0; r < KSEL; ++r) {
            unsigned m = h[0];
            #pragma unroll
            for (int w = 1; w < 8; ++w) m = m > h[w] ? m : h[w];
            vals[r] = funkey(m);
            ids[r] = (int)(m & 511u);
            #pragma unroll
            for (int w = 0; w < 8; ++w) {
                if (h[w] == m) {  // unique keys -> exactly one hit
                    ++pos[w];
                    h[w] = (pos[w] < KSEL) ? mb[lane * 132 + w * 16 + pos[w]] : 0u;
                }
            }
        }
        float mx = vals[0];
        float e[16]; float sum = 0.f;
        #pragma unroll
        for (int r = 0; r < KSEL; ++r) { e[r] = __expf(vals[r] - mx); sum += e[r]; }
        float inv = 1.f / sum;
        int n = base + lane;
        #pragma unroll
        for (int q = 0; q < 4; ++q) {
            *(float4*)(scores + n * KSEL + 4 * q) =
                make_float4(e[4*q] * inv, e[4*q+1] * inv, e[4*q+2] * inv, e[4*q+3] * inv);
            *(int4*)(sidx + n * KSEL + 4 * q) =
                make_int4(ids[4*q], ids[4*q+1], ids[4*q+2], ids[4*q+3]);
        }
        #pragma unroll
        for (int r = 0; r < KSEL; ++r) atomicAdd(&lhist[ids[r]], 1);
    }
    __syncthreads();
    for (int i = t; i < NC; i += 512) { int hv = lhist[i]; if (hv) atomicAdd(&hist[i], hv); }
}

// ---------------- kernel S: prefix scan of hist (single block) ----------------
__global__ __launch_bounds__(512) void scan_kernel(const int* __restrict__ hist,
                                                   int* __restrict__ offs,
                                                   int* __restrict__ cursor) {
    __shared__ int buf[2][NC];
    int t = threadIdx.x;
    int self = hist[t];
    buf[0][t] = self;
    __syncthreads();
    int a = 0;
    for (int d = 1; d < NC; d <<= 1) {
        int val = buf[a][t] + (t >= d ? buf[a][t - d] : 0);
        buf[1 - a][t] = val;
        __syncthreads();
        a = 1 - a;
    }
    int incl = buf[a][t];
    int excl = incl - self;
    offs[t] = excl;
    cursor[t] = excl;
    if (t == NC - 1) offs[NC] = incl;
}

// ---------------- kernel P: counting-sort scatter, 256 blocks ----------------
__global__ __launch_bounds__(256) void scatter4_kernel(
    const int* __restrict__ sidx, const float* __restrict__ scores,
    int* __restrict__ cursor, int* __restrict__ tokentab,
    float* __restrict__ scotab) {
    __shared__ int lh[NC];
    __shared__ int lbase[NC];
    const int t = threadIdx.x;
    for (int i = t; i < NC; i += 256) lh[i] = 0;
    __syncthreads();
    const int base_e = blockIdx.x * 1024;
    int myc[4];
    #pragma unroll
    for (int i = 0; i < 4; ++i) {
        int c = sidx[base_e + t + 256 * i];
        myc[i] = c;
        atomicAdd(&lh[c], 1);
    }
    __syncthreads();
    for (int i = t; i < NC; i += 256) {
        int h = lh[i];
        lbase[i] = h ? atomicAdd(&cursor[i], h) : 0;
        lh[i] = 0;
    }
    __syncthreads();
    #pragma unroll
    for (int i = 0; i < 4; ++i) {
        int e = base_e + t + 256 * i;
        int c = myc[i];
        int pos = lbase[c] + atomicAdd(&lh[c], 1);
        tokentab[pos] = (c << 16) | (e >> 4);
        scotab[pos] = scores[e];
    }
}

// ---------------- kernel C: chunk-balanced affine mixing ----------------
// One wave per 64 consecutive center-sorted pairs. W[.][lane] in 64 VGPRs,
// reloaded on (rare) center change; (token,score) broadcast via v_readlane;
// 4 independent fma chains for ILP.
__global__ __launch_bounds__(256) void mix5_kernel(
    const float* __restrict__ x, const float* __restrict__ Wv,
    const float* __restrict__ Ov, const int* __restrict__ tokentab,
    const float* __restrict__ scotab, float* __restrict__ out) {
    const int lane = threadIdx.x & 63;
    const int gw = blockIdx.x * 4 + (threadIdx.x >> 6);   // 0..4095
    const int i0 = gw * 64;

    int word_v = tokentab[i0 + lane];
    int sco_v = __float_as_int(scotab[i0 + lane]);

    float w[64];
    float ovl = 0.f;
    int cur = -1;

    #pragma unroll 1
    for (int ii = 0; ii < 64; ++ii) {
        int word = __builtin_amdgcn_readlane(word_v, ii);
        float sc = __int_as_float(__builtin_amdgcn_readlane(sco_v, ii));
        int c = word >> 16;
        int n = word & 0xffff;
        if (c != cur) {                       // wave-uniform (c is in SGPR)
            cur = c;
            #pragma unroll
            for (int g = 0; g < 64; ++g) w[g] = Wv[c * (D * D) + g * D + lane];
            ovl = Ov[c * D + lane];
        }
        const float* xr = x + n * D;          // n uniform -> scalar loads
        float a0 = 0.f, a1 = 0.f, a2 = 0.f, a3 = 0.f;
        #pragma unroll
        for (int q = 0; q < 4; ++q) {
            float4 v0 = *(const float4*)(xr + 16 * q + 0);
            float4 v1 = *(const float4*)(xr + 16 * q + 4);
            float4 v2 = *(const float4*)(xr + 16 * q + 8);
            float4 v3 = *(const float4*)(xr + 16 * q + 12);
            a0 = fmaf(v0.x, w[16*q+0], a0);  a0 = fmaf(v0.y, w[16*q+1], a0);
            a0 = fmaf(v0.z, w[16*q+2], a0);  a0 = fmaf(v0.w, w[16*q+3], a0);
            a1 = fmaf(v1.x, w[16*q+4], a1);  a1 = fmaf(v1.y, w[16*q+5], a1);
            a1 = fmaf(v1.z, w[16*q+6], a1);  a1 = fmaf(v1.w, w[16*q+7], a1);
            a2 = fmaf(v2.x, w[16*q+8], a2);  a2 = fmaf(v2.y, w[16*q+9], a2);
            a2 = fmaf(v2.z, w[16*q+10], a2); a2 = fmaf(v2.w, w[16*q+11], a2);
            a3 = fmaf(v3.x, w[16*q+12], a3); a3 = fmaf(v3.y, w[16*q+13], a3);
            a3 = fmaf(v3.z, w[16*q+14], a3); a3 = fmaf(v3.w, w[16*q+15], a3);
        }
        float a = (a0 + a1) + (a2 + a3);
        unsafeAtomicAdd(out + n * D + lane, sc * (a + ovl));
    }
}

extern "C" void kernel_launch(void* const* d_in, const int* in_sizes, int n_in,
                              void* d_out, int out_size, void* d_ws, size_t ws_size,
                              hipStream_t stream) {
    const float* x    = (const float*)d_in[0];
    const float* ctrs = (const float*)d_in[1];
    const float* Wv   = (const float*)d_in[2];
    const float* Ov   = (const float*)d_in[3];
    float* out = (float*)d_out;

    float* c2       = (float*)d_ws;                    // 512
    int*   hist     = (int*)d_ws + 512;                // 512
    int*   offs     = (int*)d_ws + 1024;               // 513 (reserve 1024)
    int*   cursor   = (int*)d_ws + 2048;               // 512 (reserve 512)
    float* scores   = (float*)d_ws + 2560;             // 262144
    int*   sidx     = (int*)d_ws + 2560 + 262144;      // 262144
    int*   tokentab = (int*)d_ws + 2560 + 2 * 262144;  // 262144
    float* scotab   = (float*)d_ws + 2560 + 3 * 262144;// 262144

    hipLaunchKernelGGL(prep_kernel, dim3(1024), dim3(256), 0, stream,
                       (float4*)out, hist, ctrs, c2);
    hipLaunchKernelGGL(topk6_kernel, dim3(N_TOK / 64), dim3(512), 0, stream,
                       x, ctrs, c2, scores, sidx, hist);
    hipLaunchKernelGGL(scan_kernel, dim3(1), dim3(512), 0, stream, hist, offs, cursor);
    hipLaunchKernelGGL(scatter4_kernel, dim3(256), dim3(256), 0, stream,
                       sidx, scores, cursor, tokentab, scotab);
    hipLaunchKernelGGL(mix5_kernel, dim3(1024), dim3(256), 0, stream,
                       x, Wv, Ov, tokentab, scotab, out);
}

// Round 6
// 219.234 us; speedup vs baseline: 1.4422x; 1.4422x over previous
//
#include <hip/hip_runtime.h>

#define N_TOK 16384
#define D 64
#define NC 512
#define KSEL 16

// ---------------- kernel P0: zero out + zero hist + center norms ----------------
__global__ void prep_kernel(float4* __restrict__ out4, int* __restrict__ hist,
                            const float* __restrict__ ctrs, float* __restrict__ c2) {
    int i = blockIdx.x * 256 + threadIdx.x;
    out4[i] = make_float4(0.f, 0.f, 0.f, 0.f);
    if (i < NC) {
        const float4* row = (const float4*)(ctrs + i * D);
        float s = 0.f;
        #pragma unroll
        for (int q = 0; q < D / 4; ++q) {
            float4 v = row[q];
            s += v.x * v.x + v.y * v.y + v.z * v.z + v.w * v.w;
        }
        c2[i] = s;
    } else if (i < 2 * NC) {
        hist[i - NC] = 0;
    }
}

__device__ __forceinline__ unsigned fkey(float f) {
    unsigned u = __float_as_uint(f);
    return (u & 0x80000000u) ? ~u : (u | 0x80000000u);
}
__device__ __forceinline__ float funkey(unsigned k) {
    unsigned u = (k & 0x80000000u) ? (k & 0x7fffffffu) : ~k;
    return __uint_as_float(u);
}

// ---------------- kernel B: dist + top-16 + softmax, lane = token ----------------
// 512 threads = 8 waves; lane L <-> token base+L; wave wi owns centers
// {p*64 + wi*8 .. +7} across 8 phases. Selection = STREAMING sorted top-16 in
// registers (bubble cascade) -> live set ~110 regs, no skey[64] array, no spill.
// Keys: fkey(score) with low 9 bits = center id (globally unique -> exact merge).
__global__ __launch_bounds__(512) void topk7_kernel(
    const float* __restrict__ x, const float* __restrict__ ctrs,
    const float* __restrict__ c2, float* __restrict__ scores,
    int* __restrict__ sidx, int* __restrict__ hist) {
    __shared__ __align__(16) unsigned char pool[35840];
    float* xs = (float*)pool;                 // [64][68]  17408 B
    float* slab = (float*)(pool + 17408);     // [64][64]  16384 B (phase centers)
    int* lhist = (int*)(pool + 33792);        // [512]      2048 B
    unsigned* mb = (unsigned*)pool;           // overlays xs+slab (both dead then)

    const int t = threadIdx.x;
    const int lane = t & 63;
    const int wi = t >> 6;
    const int base = blockIdx.x * 64;

    if (t < NC) lhist[t] = 0;

    // stage x tile -> xs (stride 68: conflict-free b128 per-lane reads)
    #pragma unroll
    for (int i = 0; i < 2; ++i) {
        int e = t + 512 * i;
        int r = e >> 4, j = e & 15;
        float4 v = *(const float4*)(x + (base + r) * D + j * 4);
        *(float4*)(xs + r * 68 + j * 4) = v;
    }
    __syncthreads();

    // own token's x row -> 64 VGPRs
    float xr[64];
    #pragma unroll
    for (int q = 0; q < 16; ++q) {
        float4 v = *(const float4*)(xs + lane * 68 + q * 4);
        xr[4 * q + 0] = v.x; xr[4 * q + 1] = v.y;
        xr[4 * q + 2] = v.z; xr[4 * q + 3] = v.w;
    }

    // running top-16, sorted descending; all real keys > 0
    unsigned run[KSEL];
    #pragma unroll
    for (int r = 0; r < KSEL; ++r) run[r] = 0u;

    // prefetch phase-0 centers into regs
    float4 pre0, pre1;
    {
        int r0 = t >> 4, j0 = t & 15;
        pre0 = *(const float4*)(ctrs + r0 * D + j0 * 4);
        int e1 = t + 512, r1 = e1 >> 4, j1 = e1 & 15;
        pre1 = *(const float4*)(ctrs + r1 * D + j1 * 4);
    }

    #pragma unroll 1
    for (int p = 0; p < 8; ++p) {
        __syncthreads();  // slab free (previous phase's reads done)
        {
            int r0 = t >> 4, j0 = t & 15;
            *(float4*)(slab + r0 * D + j0 * 4) = pre0;
            int e1 = t + 512, r1 = e1 >> 4, j1 = e1 & 15;
            *(float4*)(slab + r1 * D + j1 * 4) = pre1;
        }
        if (p < 7) {  // prefetch next phase during compute
            int r0 = t >> 4, j0 = t & 15;
            pre0 = *(const float4*)(ctrs + ((p + 1) * 64 + r0) * D + j0 * 4);
            int e1 = t + 512, r1 = e1 >> 4, j1 = e1 & 15;
            pre1 = *(const float4*)(ctrs + ((p + 1) * 64 + r1) * D + j1 * 4);
        }
        __syncthreads();  // slab ready

        #pragma unroll
        for (int jc = 0; jc < 8; ++jc) {
            const float* row = slab + (wi * 8 + jc) * D;  // wave-uniform broadcast
            float a0 = 0.f, a1 = 0.f;
            #pragma unroll
            for (int q = 0; q < 8; ++q) {
                float4 w0 = *(const float4*)(row + q * 8);
                float4 w1 = *(const float4*)(row + q * 8 + 4);
                a0 = fmaf(xr[8*q+0], w0.x, a0); a0 = fmaf(xr[8*q+1], w0.y, a0);
                a0 = fmaf(xr[8*q+2], w0.z, a0); a0 = fmaf(xr[8*q+3], w0.w, a0);
                a1 = fmaf(xr[8*q+4], w1.x, a1); a1 = fmaf(xr[8*q+5], w1.y, a1);
                a1 = fmaf(xr[8*q+6], w1.z, a1); a1 = fmaf(xr[8*q+7], w1.w, a1);
            }
            int cg = p * 64 + wi * 8 + jc;
            float sc = fmaf(2.f, a0 + a1, -c2[cg]);   // wave-uniform -> scalar load
            unsigned k = (fkey(sc) & 0xFFFFFE00u) | (unsigned)cg;
            if (k > run[KSEL - 1]) {       // divergent guard; exec-masked cascade
                #pragma unroll
                for (int r = 0; r < KSEL; ++r) {
                    unsigned mx = run[r] > k ? run[r] : k;
                    unsigned mn = run[r] > k ? k : run[r];
                    run[r] = mx; k = mn;
                }
            }
        }
    }

    __syncthreads();  // slab reads done; xs dead -> mb overlay safe
    {
        uint4* dst = (uint4*)(mb + lane * 132 + wi * 16);
        dst[0] = make_uint4(run[0], run[1], run[2], run[3]);
        dst[1] = make_uint4(run[4], run[5], run[6], run[7]);
        dst[2] = make_uint4(run[8], run[9], run[10], run[11]);
        dst[3] = make_uint4(run[12], run[13], run[14], run[15]);
    }
    __syncthreads();

    if (wi == 0) {  // 8-way tournament merge per lane (= per token), exact
        unsigned h[8]; int pos[8];
        #pragma unroll
        for (int w = 0; w < 8; ++w) { pos[w] = 0; h[w] = mb[lane * 132 + w * 16]; }
        float vals[16]; int ids[16];
        #pragma unroll
        for (int r = 0; r < KSEL; ++r) {
            unsigned m = h[0];
            #pragma unroll
            for (int w = 1; w < 8; ++w) m = m > h[w] ? m : h[w];
            vals[r] = funkey(m);
            ids[r] = (int)(m & 511u);
            #pragma unroll
            for (int w = 0; w < 8; ++w) {
                if (h[w] == m) {  // unique keys -> exactly one hit
                    ++pos[w];
                    h[w] = (pos[w] < KSEL) ? mb[lane * 132 + w * 16 + pos[w]] : 0u;
                }
            }
        }
        float mx = vals[0];
        float e[16]; float sum = 0.f;
        #pragma unroll
        for (int r = 0; r < KSEL; ++r) { e[r] = __expf(vals[r] - mx); sum += e[r]; }
        float inv = 1.f / sum;
        int n = base + lane;
        #pragma unroll
        for (int q = 0; q < 4; ++q) {
            *(float4*)(scores + n * KSEL + 4 * q) =
                make_float4(e[4*q] * inv, e[4*q+1] * inv, e[4*q+2] * inv, e[4*q+3] * inv);
            *(int4*)(sidx + n * KSEL + 4 * q) =
                make_int4(ids[4*q], ids[4*q+1], ids[4*q+2], ids[4*q+3]);
        }
        #pragma unroll
        for (int r = 0; r < KSEL; ++r) atomicAdd(&lhist[ids[r]], 1);
    }
    __syncthreads();
    for (int i = t; i < NC; i += 512) { int hv = lhist[i]; if (hv) atomicAdd(&hist[i], hv); }
}

// ---------------- kernel S: prefix scan of hist (single block) ----------------
__global__ __launch_bounds__(512) void scan_kernel(const int* __restrict__ hist,
                                                   int* __restrict__ offs,
                                                   int* __restrict__ cursor) {
    __shared__ int buf[2][NC];
    int t = threadIdx.x;
    int self = hist[t];
    buf[0][t] = self;
    __syncthreads();
    int a = 0;
    for (int d = 1; d < NC; d <<= 1) {
        int val = buf[a][t] + (t >= d ? buf[a][t - d] : 0);
        buf[1 - a][t] = val;
        __syncthreads();
        a = 1 - a;
    }
    int incl = buf[a][t];
    int excl = incl - self;
    offs[t] = excl;
    cursor[t] = excl;
    if (t == NC - 1) offs[NC] = incl;
}

// ---------------- kernel P: counting-sort scatter, 256 blocks ----------------
// tokentab entry packs (c << 18) | e, where e = token*16 + slot (original order).
__global__ __launch_bounds__(256) void scatter4_kernel(
    const int* __restrict__ sidx, const float* __restrict__ scores,
    int* __restrict__ cursor, int* __restrict__ tokentab,
    float* __restrict__ scotab) {
    __shared__ int lh[NC];
    __shared__ int lbase[NC];
    const int t = threadIdx.x;
    for (int i = t; i < NC; i += 256) lh[i] = 0;
    __syncthreads();
    const int base_e = blockIdx.x * 1024;
    int myc[4];
    #pragma unroll
    for (int i = 0; i < 4; ++i) {
        int c = sidx[base_e + t + 256 * i];
        myc[i] = c;
        atomicAdd(&lh[c], 1);
    }
    __syncthreads();
    for (int i = t; i < NC; i += 256) {
        int h = lh[i];
        lbase[i] = h ? atomicAdd(&cursor[i], h) : 0;
        lh[i] = 0;
    }
    __syncthreads();
    #pragma unroll
    for (int i = 0; i < 4; ++i) {
        int e = base_e + t + 256 * i;
        int c = myc[i];
        int pos = lbase[c] + atomicAdd(&lh[c], 1);
        tokentab[pos] = (c << 18) | e;
        scotab[pos] = scores[e];
    }
}

// ---------------- kernel C (store path): contribution store, no atomics ----------
// One wave per 64 center-sorted pairs; W[.][lane] in 64 VGPRs reloaded on center
// change; each pair's 64-dim result is STORED to cont[e][lane] (e = token-major
// pair index) for a later 16-way reduce. Zero atomic contention.
__global__ __launch_bounds__(256) void mix6_kernel(
    const float* __restrict__ x, const float* __restrict__ Wv,
    const float* __restrict__ Ov, const int* __restrict__ tokentab,
    const float* __restrict__ scotab, float* __restrict__ cont) {
    const int lane = threadIdx.x & 63;
    const int gw = blockIdx.x * 4 + (threadIdx.x >> 6);   // 0..4095
    const int i0 = gw * 64;

    int word_v = tokentab[i0 + lane];
    int sco_v = __float_as_int(scotab[i0 + lane]);

    float w[64];
    float ovl = 0.f;
    int cur = -1;

    #pragma unroll 1
    for (int ii = 0; ii < 64; ++ii) {
        int word = __builtin_amdgcn_readlane(word_v, ii);
        float sc = __int_as_float(__builtin_amdgcn_readlane(sco_v, ii));
        int c = word >> 18;
        int e = word & 0x3FFFF;
        int n = e >> 4;
        if (c != cur) {                       // wave-uniform (c in SGPR)
            cur = c;
            #pragma unroll
            for (int g = 0; g < 64; ++g) w[g] = Wv[c * (D * D) + g * D + lane];
            ovl = Ov[c * D + lane];
        }
        const float* xr = x + n * D;          // n uniform -> scalar loads
        float a0 = 0.f, a1 = 0.f, a2 = 0.f, a3 = 0.f;
        #pragma unroll
        for (int q = 0; q < 4; ++q) {
            float4 v0 = *(const float4*)(xr + 16 * q + 0);
            float4 v1 = *(const float4*)(xr + 16 * q + 4);
            float4 v2 = *(const float4*)(xr + 16 * q + 8);
            float4 v3 = *(const float4*)(xr + 16 * q + 12);
            a0 = fmaf(v0.x, w[16*q+0], a0);  a0 = fmaf(v0.y, w[16*q+1], a0);
            a0 = fmaf(v0.z, w[16*q+2], a0);  a0 = fmaf(v0.w, w[16*q+3], a0);
            a1 = fmaf(v1.x, w[16*q+4], a1);  a1 = fmaf(v1.y, w[16*q+5], a1);
            a1 = fmaf(v1.z, w[16*q+6], a1);  a1 = fmaf(v1.w, w[16*q+7], a1);
            a2 = fmaf(v2.x, w[16*q+8], a2);  a2 = fmaf(v2.y, w[16*q+9], a2);
            a2 = fmaf(v2.z, w[16*q+10], a2); a2 = fmaf(v2.w, w[16*q+11], a2);
            a3 = fmaf(v3.x, w[16*q+12], a3); a3 = fmaf(v3.y, w[16*q+13], a3);
            a3 = fmaf(v3.z, w[16*q+14], a3); a3 = fmaf(v3.w, w[16*q+15], a3);
        }
        float a = (a0 + a1) + (a2 + a3);
        cont[(size_t)e * D + lane] = sc * (a + ovl);
    }
}

// reduce: out[n][l] = sum_{j<16} cont[n*16+j][l]
__global__ __launch_bounds__(256) void reduce_kernel(const float* __restrict__ cont,
                                                     float* __restrict__ out) {
    int idx = blockIdx.x * 256 + threadIdx.x;     // 0..1048575
    int n = idx >> 6, l = idx & 63;
    const float* p = cont + (size_t)n * (KSEL * D) + l;
    float s = 0.f;
    #pragma unroll
    for (int j = 0; j < KSEL; ++j) s += p[j * D];
    out[idx] = s;
}

// ---------------- kernel C (atomic fallback, if ws too small) ----------------
__global__ __launch_bounds__(256) void mix_atomic_kernel(
    const float* __restrict__ x, const float* __restrict__ Wv,
    const float* __restrict__ Ov, const int* __restrict__ tokentab,
    const float* __restrict__ scotab, float* __restrict__ out) {
    const int lane = threadIdx.x & 63;
    const int gw = blockIdx.x * 4 + (threadIdx.x >> 6);
    const int i0 = gw * 64;
    int word_v = tokentab[i0 + lane];
    int sco_v = __float_as_int(scotab[i0 + lane]);
    float w[64];
    float ovl = 0.f;
    int cur = -1;
    #pragma unroll 1
    for (int ii = 0; ii < 64; ++ii) {
        int word = __builtin_amdgcn_readlane(word_v, ii);
        float sc = __int_as_float(__builtin_amdgcn_readlane(sco_v, ii));
        int c = word >> 18;
        int n = (word & 0x3FFFF) >> 4;
        if (c != cur) {
            cur = c;
            #pragma unroll
            for (int g = 0; g < 64; ++g) w[g] = Wv[c * (D * D) + g * D + lane];
            ovl = Ov[c * D + lane];
        }
        const float* xr = x + n * D;
        float a0 = 0.f, a1 = 0.f, a2 = 0.f, a3 = 0.f;
        #pragma unroll
        for (int q = 0; q < 4; ++q) {
            float4 v0 = *(const float4*)(xr + 16 * q + 0);
            float4 v1 = *(const float4*)(xr + 16 * q + 4);
            float4 v2 = *(const float4*)(xr + 16 * q + 8);
            float4 v3 = *(const float4*)(xr + 16 * q + 12);
            a0 = fmaf(v0.x, w[16*q+0], a0);  a0 = fmaf(v0.y, w[16*q+1], a0);
            a0 = fmaf(v0.z, w[16*q+2], a0);  a0 = fmaf(v0.w, w[16*q+3], a0);
            a1 = fmaf(v1.x, w[16*q+4], a1);  a1 = fmaf(v1.y, w[16*q+5], a1);
            a1 = fmaf(v1.z, w[16*q+6], a1);  a1 = fmaf(v1.w, w[16*q+7], a1);
            a2 = fmaf(v2.x, w[16*q+8], a2);  a2 = fmaf(v2.y, w[16*q+9], a2);
            a2 = fmaf(v2.z, w[16*q+10], a2); a2 = fmaf(v2.w, w[16*q+11], a2);
            a3 = fmaf(v3.x, w[16*q+12], a3); a3 = fmaf(v3.y, w[16*q+13], a3);
            a3 = fmaf(v3.z, w[16*q+14], a3); a3 = fmaf(v3.w, w[16*q+15], a3);
        }
        float a = (a0 + a1) + (a2 + a3);
        unsafeAtomicAdd(out + n * D + lane, sc * (a + ovl));
    }
}

extern "C" void kernel_launch(void* const* d_in, const int* in_sizes, int n_in,
                              void* d_out, int out_size, void* d_ws, size_t ws_size,
                              hipStream_t stream) {
    const float* x    = (const float*)d_in[0];
    const float* ctrs = (const float*)d_in[1];
    const float* Wv   = (const float*)d_in[2];
    const float* Ov   = (const float*)d_in[3];
    float* out = (float*)d_out;

    float* c2       = (float*)d_ws;                    // 512
    int*   hist     = (int*)d_ws + 512;                // 512
    int*   offs     = (int*)d_ws + 1024;               // 513 (reserve 1024)
    int*   cursor   = (int*)d_ws + 2048;               // 512 (reserve 512)
    float* scores   = (float*)d_ws + 2560;             // 262144
    int*   sidx     = (int*)d_ws + 2560 + 262144;      // 262144
    int*   tokentab = (int*)d_ws + 2560 + 2 * 262144;  // 262144
    float* scotab   = (float*)d_ws + 2560 + 3 * 262144;// 262144
    float* cont     = (float*)d_ws + 2560 + 4 * 262144;// 16777216 (64 MB)

    const size_t need_bytes = ((size_t)2560 + 4 * 262144 + 16777216) * 4;
    const bool use_store = ws_size >= need_bytes;

    hipLaunchKernelGGL(prep_kernel, dim3(1024), dim3(256), 0, stream,
                       (float4*)out, hist, ctrs, c2);
    hipLaunchKernelGGL(topk7_kernel, dim3(N_TOK / 64), dim3(512), 0, stream,
                       x, ctrs, c2, scores, sidx, hist);
    hipLaunchKernelGGL(scan_kernel, dim3(1), dim3(512), 0, stream, hist, offs, cursor);
    hipLaunchKernelGGL(scatter4_kernel, dim3(256), dim3(256), 0, stream,
                       sidx, scores, cursor, tokentab, scotab);
    if (use_store) {
        hipLaunchKernelGGL(mix6_kernel, dim3(1024), dim3(256), 0, stream,
                           x, Wv, Ov, tokentab, scotab, cont);
        hipLaunchKernelGGL(reduce_kernel, dim3(4096), dim3(256), 0, stream,
                           cont, out);
    } else {
        hipLaunchKernelGGL(mix_atomic_kernel, dim3(1024), dim3(256), 0, stream,
                           x, Wv, Ov, tokentab, scotab, out);
    }
}

// Round 7
// 202.255 us; speedup vs baseline: 1.5633x; 1.0840x over previous
//
#include <hip/hip_runtime.h>

#define N_TOK 16384
#define D 64
#define NC 512
#define KSEL 16

// ---------------- kernel P0: zero out + zero hist + center norms ----------------
__global__ void prep_kernel(float4* __restrict__ out4, int* __restrict__ hist,
                            const float* __restrict__ ctrs, float* __restrict__ c2) {
    int i = blockIdx.x * 256 + threadIdx.x;
    out4[i] = make_float4(0.f, 0.f, 0.f, 0.f);
    if (i < NC) {
        const float4* row = (const float4*)(ctrs + i * D);
        float s = 0.f;
        #pragma unroll
        for (int q = 0; q < D / 4; ++q) {
            float4 v = row[q];
            s += v.x * v.x + v.y * v.y + v.z * v.z + v.w * v.w;
        }
        c2[i] = s;
    } else if (i < 2 * NC) {
        hist[i - NC] = 0;
    }
}

__device__ __forceinline__ unsigned fkey(float f) {
    unsigned u = __float_as_uint(f);
    return (u & 0x80000000u) ? ~u : (u | 0x80000000u);
}
__device__ __forceinline__ float funkey(unsigned k) {
    unsigned u = (k & 0x80000000u) ? (k & 0x7fffffffu) : ~k;
    return __uint_as_float(u);
}

// ---------------- kernel B: dist + top-16 + softmax, lane = token ----------------
// 512 threads = 8 waves; lane L <-> token base+L; wave wi owns centers
// {p*64 + wi*8 .. +7} across 8 phases. Selection = streaming sorted top-16 in
// registers (bubble cascade). Keys: fkey(score) low 9 bits = center id (unique).
__global__ __launch_bounds__(512) void topk7_kernel(
    const float* __restrict__ x, const float* __restrict__ ctrs,
    const float* __restrict__ c2, float* __restrict__ scores,
    int* __restrict__ sidx, int* __restrict__ hist) {
    __shared__ __align__(16) unsigned char pool[35840];
    float* xs = (float*)pool;                 // [64][68]  17408 B
    float* slab = (float*)(pool + 17408);     // [64][64]  16384 B (phase centers)
    int* lhist = (int*)(pool + 33792);        // [512]      2048 B
    unsigned* mb = (unsigned*)pool;           // overlays xs+slab (both dead then)

    const int t = threadIdx.x;
    const int lane = t & 63;
    const int wi = t >> 6;
    const int base = blockIdx.x * 64;

    if (t < NC) lhist[t] = 0;

    // stage x tile -> xs (stride 68: conflict-free b128 per-lane reads)
    #pragma unroll
    for (int i = 0; i < 2; ++i) {
        int e = t + 512 * i;
        int r = e >> 4, j = e & 15;
        float4 v = *(const float4*)(x + (base + r) * D + j * 4);
        *(float4*)(xs + r * 68 + j * 4) = v;
    }
    __syncthreads();

    // own token's x row -> 64 VGPRs
    float xr[64];
    #pragma unroll
    for (int q = 0; q < 16; ++q) {
        float4 v = *(const float4*)(xs + lane * 68 + q * 4);
        xr[4 * q + 0] = v.x; xr[4 * q + 1] = v.y;
        xr[4 * q + 2] = v.z; xr[4 * q + 3] = v.w;
    }

    // running top-16, sorted descending; all real keys > 0
    unsigned run[KSEL];
    #pragma unroll
    for (int r = 0; r < KSEL; ++r) run[r] = 0u;

    // prefetch phase-0 centers into regs
    float4 pre0, pre1;
    {
        int r0 = t >> 4, j0 = t & 15;
        pre0 = *(const float4*)(ctrs + r0 * D + j0 * 4);
        int e1 = t + 512, r1 = e1 >> 4, j1 = e1 & 15;
        pre1 = *(const float4*)(ctrs + r1 * D + j1 * 4);
    }

    #pragma unroll 1
    for (int p = 0; p < 8; ++p) {
        __syncthreads();  // slab free (previous phase's reads done)
        {
            int r0 = t >> 4, j0 = t & 15;
            *(float4*)(slab + r0 * D + j0 * 4) = pre0;
            int e1 = t + 512, r1 = e1 >> 4, j1 = e1 & 15;
            *(float4*)(slab + r1 * D + j1 * 4) = pre1;
        }
        if (p < 7) {  // prefetch next phase during compute
            int r0 = t >> 4, j0 = t & 15;
            pre0 = *(const float4*)(ctrs + ((p + 1) * 64 + r0) * D + j0 * 4);
            int e1 = t + 512, r1 = e1 >> 4, j1 = e1 & 15;
            pre1 = *(const float4*)(ctrs + ((p + 1) * 64 + r1) * D + j1 * 4);
        }
        __syncthreads();  // slab ready

        #pragma unroll
        for (int jc = 0; jc < 8; ++jc) {
            const float* row = slab + (wi * 8 + jc) * D;  // wave-uniform broadcast
            float a0 = 0.f, a1 = 0.f;
            #pragma unroll
            for (int q = 0; q < 8; ++q) {
                float4 w0 = *(const float4*)(row + q * 8);
                float4 w1 = *(const float4*)(row + q * 8 + 4);
                a0 = fmaf(xr[8*q+0], w0.x, a0); a0 = fmaf(xr[8*q+1], w0.y, a0);
                a0 = fmaf(xr[8*q+2], w0.z, a0); a0 = fmaf(xr[8*q+3], w0.w, a0);
                a1 = fmaf(xr[8*q+4], w1.x, a1); a1 = fmaf(xr[8*q+5], w1.y, a1);
                a1 = fmaf(xr[8*q+6], w1.z, a1); a1 = fmaf(xr[8*q+7], w1.w, a1);
            }
            int cg = p * 64 + wi * 8 + jc;
            float sc = fmaf(2.f, a0 + a1, -c2[cg]);   // wave-uniform -> scalar load
            unsigned k = (fkey(sc) & 0xFFFFFE00u) | (unsigned)cg;
            if (k > run[KSEL - 1]) {       // divergent guard; exec-masked cascade
                #pragma unroll
                for (int r = 0; r < KSEL; ++r) {
                    unsigned mx = run[r] > k ? run[r] : k;
                    unsigned mn = run[r] > k ? k : run[r];
                    run[r] = mx; k = mn;
                }
            }
        }
    }

    __syncthreads();  // slab reads done; xs dead -> mb overlay safe
    {
        uint4* dst = (uint4*)(mb + lane * 132 + wi * 16);
        dst[0] = make_uint4(run[0], run[1], run[2], run[3]);
        dst[1] = make_uint4(run[4], run[5], run[6], run[7]);
        dst[2] = make_uint4(run[8], run[9], run[10], run[11]);
        dst[3] = make_uint4(run[12], run[13], run[14], run[15]);
    }
    __syncthreads();

    if (wi == 0) {  // 8-way tournament merge per lane (= per token), exact
        unsigned h[8]; int pos[8];
        #pragma unroll
        for (int w = 0; w < 8; ++w) { pos[w] = 0; h[w] = mb[lane * 132 + w * 16]; }
        float vals[16]; int ids[16];
        #pragma unroll
        for (int r = 0; r < KSEL; ++r) {
            unsigned m = h[0];
            #pragma unroll
            for (int w = 1; w < 8; ++w) m = m > h[w] ? m : h[w];
            vals[r] = funkey(m);
            ids[r] = (int)(m & 511u);
            #pragma unroll
            for (int w = 0; w < 8; ++w) {
                if (h[w] == m) {  // unique keys -> exactly one hit
                    ++pos[w];
                    h[w] = (pos[w] < KSEL) ? mb[lane * 132 + w * 16 + pos[w]] : 0u;
                }
            }
        }
        float mx = vals[0];
        float e[16]; float sum = 0.f;
        #pragma unroll
        for (int r = 0; r < KSEL; ++r) { e[r] = __expf(vals[r] - mx); sum += e[r]; }
        float inv = 1.f / sum;
        int n = base + lane;
        #pragma unroll
        for (int q = 0; q < 4; ++q) {
            *(float4*)(scores + n * KSEL + 4 * q) =
                make_float4(e[4*q] * inv, e[4*q+1] * inv, e[4*q+2] * inv, e[4*q+3] * inv);
            *(int4*)(sidx + n * KSEL + 4 * q) =
                make_int4(ids[4*q], ids[4*q+1], ids[4*q+2], ids[4*q+3]);
        }
        #pragma unroll
        for (int r = 0; r < KSEL; ++r) atomicAdd(&lhist[ids[r]], 1);
    }
    __syncthreads();
    for (int i = t; i < NC; i += 512) { int hv = lhist[i]; if (hv) atomicAdd(&hist[i], hv); }
}

// ---------------- kernel S: prefix scan of hist (single block) ----------------
__global__ __launch_bounds__(512) void scan_kernel(const int* __restrict__ hist,
                                                   int* __restrict__ offs,
                                                   int* __restrict__ cursor) {
    __shared__ int buf[2][NC];
    int t = threadIdx.x;
    int self = hist[t];
    buf[0][t] = self;
    __syncthreads();
    int a = 0;
    for (int d = 1; d < NC; d <<= 1) {
        int val = buf[a][t] + (t >= d ? buf[a][t - d] : 0);
        buf[1 - a][t] = val;
        __syncthreads();
        a = 1 - a;
    }
    int incl = buf[a][t];
    int excl = incl - self;
    offs[t] = excl;
    cursor[t] = excl;
    if (t == NC - 1) offs[NC] = incl;
}

// ---------------- kernel P: counting-sort scatter, 256 blocks ----------------
// tokentab entry packs (c << 18) | e, where e = token*16 + slot (original order).
__global__ __launch_bounds__(256) void scatter4_kernel(
    const int* __restrict__ sidx, const float* __restrict__ scores,
    int* __restrict__ cursor, int* __restrict__ tokentab,
    float* __restrict__ scotab) {
    __shared__ int lh[NC];
    __shared__ int lbase[NC];
    const int t = threadIdx.x;
    for (int i = t; i < NC; i += 256) lh[i] = 0;
    __syncthreads();
    const int base_e = blockIdx.x * 1024;
    int myc[4];
    #pragma unroll
    for (int i = 0; i < 4; ++i) {
        int c = sidx[base_e + t + 256 * i];
        myc[i] = c;
        atomicAdd(&lh[c], 1);
    }
    __syncthreads();
    for (int i = t; i < NC; i += 256) {
        int h = lh[i];
        lbase[i] = h ? atomicAdd(&cursor[i], h) : 0;
        lh[i] = 0;
    }
    __syncthreads();
    #pragma unroll
    for (int i = 0; i < 4; ++i) {
        int e = base_e + t + 256 * i;
        int c = myc[i];
        int pos = lbase[c] + atomicAdd(&lh[c], 1);
        tokentab[pos] = (c << 18) | e;
        scotab[pos] = scores[e];
    }
}

// ---------------- kernel C: run-split affine mixing, atomic accumulate ----------
// One wave per 32 center-sorted pairs (8192 waves). Each chunk is split into
// same-center runs; W[.][lane] loaded unconditionally at run start (straight-line
// def -> VGPR-resident, no AGPR traffic). x rows are wave-uniform scalar loads;
// latency hidden by 8 waves/SIMD TLP. Output via fire-and-forget f32 atomics.
__global__ __launch_bounds__(256) void mix7_kernel(
    const float* __restrict__ x, const float* __restrict__ Wv,
    const float* __restrict__ Ov, const int* __restrict__ tokentab,
    const float* __restrict__ scotab, float* __restrict__ out) {
    const int lane = threadIdx.x & 63;
    const int gw = blockIdx.x * 4 + (threadIdx.x >> 6);   // 0..8191
    const int i0 = gw * 32;

    int word_v = tokentab[i0 + (lane & 31)];
    int sco_v = __float_as_int(scotab[i0 + (lane & 31)]);

    int ii = 0;
    #pragma unroll 1
    while (ii < 32) {
        const int c = __builtin_amdgcn_readlane(word_v, ii) >> 18;
        // find end of this center-run (wave-uniform scalar-ish scan)
        int je = ii + 1;
        #pragma unroll 1
        while (je < 32 && (__builtin_amdgcn_readlane(word_v, je) >> 18) == c) ++je;

        // load W column for this lane: straight-line def -> VGPRs
        float w[64];
        {
            const float* Wc = Wv + c * (D * D) + lane;
            #pragma unroll
            for (int g = 0; g < 64; ++g) w[g] = Wc[g * 64];
        }
        const float ovl = Ov[c * D + lane];

        #pragma unroll 1
        for (; ii < je; ++ii) {
            int word = __builtin_amdgcn_readlane(word_v, ii);
            float sc = __int_as_float(__builtin_amdgcn_readlane(sco_v, ii));
            int n = (word & 0x3FFFF) >> 4;
            const float* xr = x + n * D;      // uniform -> scalar loads
            float a0 = 0.f, a1 = 0.f, a2 = 0.f, a3 = 0.f;
            #pragma unroll
            for (int q = 0; q < 4; ++q) {
                float4 v0 = *(const float4*)(xr + 16 * q + 0);
                float4 v1 = *(const float4*)(xr + 16 * q + 4);
                float4 v2 = *(const float4*)(xr + 16 * q + 8);
                float4 v3 = *(const float4*)(xr + 16 * q + 12);
                a0 = fmaf(v0.x, w[16*q+0], a0);  a0 = fmaf(v0.y, w[16*q+1], a0);
                a0 = fmaf(v0.z, w[16*q+2], a0);  a0 = fmaf(v0.w, w[16*q+3], a0);
                a1 = fmaf(v1.x, w[16*q+4], a1);  a1 = fmaf(v1.y, w[16*q+5], a1);
                a1 = fmaf(v1.z, w[16*q+6], a1);  a1 = fmaf(v1.w, w[16*q+7], a1);
                a2 = fmaf(v2.x, w[16*q+8], a2);  a2 = fmaf(v2.y, w[16*q+9], a2);
                a2 = fmaf(v2.z, w[16*q+10], a2); a2 = fmaf(v2.w, w[16*q+11], a2);
                a3 = fmaf(v3.x, w[16*q+12], a3); a3 = fmaf(v3.y, w[16*q+13], a3);
                a3 = fmaf(v3.z, w[16*q+14], a3); a3 = fmaf(v3.w, w[16*q+15], a3);
            }
            float a = (a0 + a1) + (a2 + a3);
            unsafeAtomicAdd(out + n * D + lane, sc * (a + ovl));
        }
    }
}

extern "C" void kernel_launch(void* const* d_in, const int* in_sizes, int n_in,
                              void* d_out, int out_size, void* d_ws, size_t ws_size,
                              hipStream_t stream) {
    const float* x    = (const float*)d_in[0];
    const float* ctrs = (const float*)d_in[1];
    const float* Wv   = (const float*)d_in[2];
    const float* Ov   = (const float*)d_in[3];
    float* out = (float*)d_out;

    float* c2       = (float*)d_ws;                    // 512
    int*   hist     = (int*)d_ws + 512;                // 512
    int*   offs     = (int*)d_ws + 1024;               // 513 (reserve 1024)
    int*   cursor   = (int*)d_ws + 2048;               // 512 (reserve 512)
    float* scores   = (float*)d_ws + 2560;             // 262144
    int*   sidx     = (int*)d_ws + 2560 + 262144;      // 262144
    int*   tokentab = (int*)d_ws + 2560 + 2 * 262144;  // 262144
    float* scotab   = (float*)d_ws + 2560 + 3 * 262144;// 262144

    hipLaunchKernelGGL(prep_kernel, dim3(1024), dim3(256), 0, stream,
                       (float4*)out, hist, ctrs, c2);
    hipLaunchKernelGGL(topk7_kernel, dim3(N_TOK / 64), dim3(512), 0, stream,
                       x, ctrs, c2, scores, sidx, hist);
    hipLaunchKernelGGL(scan_kernel, dim3(1), dim3(512), 0, stream, hist, offs, cursor);
    hipLaunchKernelGGL(scatter4_kernel, dim3(256), dim3(256), 0, stream,
                       sidx, scores, cursor, tokentab, scotab);
    hipLaunchKernelGGL(mix7_kernel, dim3(2048), dim3(256), 0, stream,
                       x, Wv, Ov, tokentab, scotab, out);
}